// Round 2
// baseline (11405.310 us; speedup 1.0000x reference)
//
#include <hip/hip_runtime.h>
#include <stdint.h>

// ---- problem constants ----
#define ENC_HID 768
#define DEC_HID 128
#define EMB_    200
#define VOCAB   32000
#define B_      32
#define S_      256
#define T_      96
#define NSTEP   95          // T-1 decode steps
#define KFC     1096        // 128 + 768 + 200
#define KPAD    1120        // 35 * 32  (K padded for BK=32)
#define MROWS   3040        // 95 * 32
#define MPAD    3072        // 24 * 128
#define NB_N    250         // 32000 / 128
#define NB_M    24          // 3072 / 128

typedef _Float16 half8 __attribute__((ext_vector_type(8)));
typedef float    floatx4 __attribute__((ext_vector_type(4)));

// ---- workspace layout (bytes), all 16B-aligned ----
#define WS_AHI  ((size_t)0)
#define WS_ALO  (WS_AHI + (size_t)MPAD*KPAD*2)            //   6,881,280
#define WS_BHI  (WS_ALO + (size_t)MPAD*KPAD*2)            //  13,762,560
#define WS_BLO  (WS_BHI + (size_t)VOCAB*KPAD*2)           //  85,442,560
#define WS_PART (WS_BLO + (size_t)VOCAB*KPAD*2)           // 157,122,560
#define WS_W1T  (WS_PART+ (size_t)NB_N*MPAD*8)            // 163,266,560
#define WS_W2T  (WS_W1T + (size_t)484*512*8)
#define WS_ENCT (WS_W2T + (size_t)64*512*8)
#define WS_GB   (WS_ENCT+ (size_t)32*128*256*4)
// total ~162 MiB

__device__ __forceinline__ float tanh_fast(float x){
  float ax = fabsf(x);
  float t = __builtin_amdgcn_exp2f(-2.8853900817779268f * ax);   // e^{-2|x|}
  float r = (1.0f - t) * __builtin_amdgcn_rcpf(1.0f + t);
  return copysignf(r, x);
}
__device__ __forceinline__ float sigmoid_fast(float x){
  float t = __builtin_amdgcn_exp2f(-1.4426950408889634f * x);
  return __builtin_amdgcn_rcpf(1.0f + t);
}

// ============ prep: transpose/pack LSTM weights (fp32 pairs), combine bias ============
__global__ void prep_weights(const float* __restrict__ W_ih,
                             const float* __restrict__ W_hh,
                             const float* __restrict__ b_ih,
                             const float* __restrict__ b_hh,
                             float2* __restrict__ W1T,
                             float2* __restrict__ W2T,
                             float* __restrict__ gbias){
  int i = blockIdx.x*blockDim.x + threadIdx.x;
  const int n1 = 484*512;
  if(i < n1){
    int kk = i >> 9, j = i & 511;
    W1T[i] = make_float2(W_ih[j*968 + 2*kk], W_ih[j*968 + 2*kk+1]);
  } else if(i < n1 + 64*512){
    int r = i - n1; int kk = r >> 9, j = r & 511;
    W2T[r] = make_float2(W_hh[j*128 + 2*kk], W_hh[j*128 + 2*kk+1]);
  } else if(i < n1 + 64*512 + 512){
    int j = i - n1 - 64*512;
    gbias[j] = b_ih[j] + b_hh[j];
  }
}

// ============ prep: encT[b][u][s] = attn_b[u] + enc[b,s,:] @ attn_W[128:,u] ============
__global__ __launch_bounds__(128) void prep_encpart(
    const float* __restrict__ enc,
    const float* __restrict__ attn_W,
    const float* __restrict__ attn_b,
    float* __restrict__ encT){
  int g = blockIdx.x;              // 1024 = 32 b * 32 s-groups
  int b = g >> 5, s0 = (g & 31) << 3;
  int u = threadIdx.x;             // 128
  __shared__ float rowsT[ENC_HID][8];
  for(int r=0;r<8;++r)
    for(int i=u;i<ENC_HID;i+=128)
      rowsT[i][r] = enc[((size_t)(b*S_ + s0 + r))*ENC_HID + i];
  __syncthreads();
  float ab = attn_b[u];
  float acc[8];
  #pragma unroll
  for(int r=0;r<8;++r) acc[r]=ab;
  for(int d=0; d<ENC_HID; ++d){
    float w = attn_W[(128+d)*128 + u];
    #pragma unroll
    for(int r=0;r<8;++r) acc[r] += rowsT[d][r]*w;
  }
  for(int r=0;r<8;++r)
    encT[((size_t)b*128 + u)*256 + (s0+r)] = acc[r];
}

// ============ prep: fc_W (fp32) -> f16 hi/lo split, B scaled x64, lo x2048 ============
__global__ void prep_B(const float* __restrict__ fcW,
                       _Float16* __restrict__ Bhi, _Float16* __restrict__ Blo){
  size_t i = (size_t)blockIdx.x*blockDim.x + threadIdx.x;   // 32000*1120 exact
  size_t row = i / KPAD; int col = (int)(i - row*KPAD);
  float x = 0.f;
  if(col < KFC) x = fcW[row*KFC + col] * 64.0f;
  _Float16 hi = (_Float16)x;
  Bhi[i] = hi;
  Blo[i] = (_Float16)((x - (float)hi) * 2048.0f);
}

// ============ zero t=0 logits slice + t=0 tokens ============
__global__ void zero_t0(float* __restrict__ out){
  int i = blockIdx.x*blockDim.x + threadIdx.x;
  if(i < B_*VOCAB){
    int b = i / VOCAB, v = i - (i/VOCAB)*VOCAB;
    out[(size_t)b*T_*VOCAB + v] = 0.f;
  } else if(i < B_*VOCAB + B_){
    int b = i - B_*VOCAB;
    out[(size_t)B_*T_*VOCAB + (size_t)b*T_] = 0.f;
  }
}

// ============ recurrence: one block per batch element, 95 steps ============
__global__ __launch_bounds__(512) void recurrence(
    const float*  __restrict__ enc,        // [32,256,768]
    const int*    __restrict__ trg,        // [32,96]
    const float*  __restrict__ embedding,  // [32000,200]
    const float*  __restrict__ attn_W,     // [896,128]
    const float*  __restrict__ attn_v,     // [128]
    const float2* __restrict__ W1T,        // [484][512] k-pairs
    const float2* __restrict__ W2T,        // [64][512]
    const float*  __restrict__ gbias,      // [512]
    const float*  __restrict__ encT,       // [32,128,256]
    _Float16* __restrict__ Ahi, _Float16* __restrict__ Alo){
  int b = blockIdx.x;
  int tid = threadIdx.x;
  __shared__ float h[128], c[128], hp[128], ea[256], w_[768], emb[200], xg[512], vl[128], red[8];
  if(tid<128){ h[tid]=0.f; c[tid]=0.f; vl[tid]=attn_v[tid]; }
  __syncthreads();
  const float LOG2E = 1.4426950408889634f;
  for(int t=0;t<NSTEP;++t){
    int tok = trg[b*T_ + t];
    if(tid<200) emb[tid] = embedding[(size_t)tok*EMB_ + tid];
    if(tid<128){
      float acc=0.f;
      #pragma unroll 4
      for(int k=0;k<128;++k) acc += h[k]*attn_W[k*128+tid];
      hp[tid]=acc;
    }
    __syncthreads();
    // attention energies e[s] = sum_u v[u]*tanh(encT[u][s] + hp[u])
    if(tid<256){
      const float* ep = encT + (size_t)b*128*256 + tid;
      float acc=0.f;
      #pragma unroll 2
      for(int u=0;u<128;++u){
        float x = ep[u*256] + hp[u];
        acc += vl[u]*tanh_fast(x);
      }
      ea[tid]=acc;
    }
    __syncthreads();
    // softmax over s (block-local)
    if(tid<256){
      float v0 = ea[tid];
      for(int off=32;off;off>>=1) v0 = fmaxf(v0, __shfl_xor(v0,off));
      if((tid&63)==0) red[tid>>6]=v0;
    }
    __syncthreads();
    float mx = fmaxf(fmaxf(red[0],red[1]),fmaxf(red[2],red[3]));
    if(tid<256){
      float p = __builtin_amdgcn_exp2f((ea[tid]-mx)*LOG2E);
      ea[tid]=p;
      for(int off=32;off;off>>=1) p += __shfl_xor(p,off);
      if((tid&63)==0) red[4+(tid>>6)]=p;
    }
    __syncthreads();
    float sum = red[4]+red[5]+red[6]+red[7];
    if(tid<256) ea[tid] = ea[tid]/sum;
    __syncthreads();
    // weighted[d] = sum_s a[s]*enc[b,s,d]   (2 d's per lane, float2 loads)
    if(tid<384){
      const float2* er2 = (const float2*)(enc + (size_t)b*S_*ENC_HID);
      float a0=0.f, a1=0.f;
      #pragma unroll 4
      for(int s=0;s<256;++s){
        float2 w2 = er2[s*384 + tid];
        float as = ea[s];
        a0 += as*w2.x;
        a1 += as*w2.y;
      }
      w_[2*tid]=a0; w_[2*tid+1]=a1;
    }
    __syncthreads();
    // gates[j] = gbias + emb@W_ih[:,:200].T + weighted@W_ih[:,200:].T + h@W_hh.T
    {
      int j = tid;
      float g = gbias[j];
      const float2* w1 = W1T + j;
      #pragma unroll 4
      for(int kk=0;kk<100;++kk){
        float2 w = w1[kk*512];
        g += emb[2*kk]*w.x + emb[2*kk+1]*w.y;
      }
      #pragma unroll 4
      for(int kk=100;kk<484;++kk){
        float2 w = w1[kk*512];
        g += w_[2*kk-200]*w.x + w_[2*kk-199]*w.y;
      }
      const float2* w2p = W2T + j;
      #pragma unroll 4
      for(int kk=0;kk<64;++kk){
        float2 w = w2p[kk*512];
        g += h[2*kk]*w.x + h[2*kk+1]*w.y;
      }
      xg[j] = g;
    }
    __syncthreads();
    // LSTM cell (pytorch gate order i,f,g,o)
    if(tid<128){
      float gi = xg[tid], gf = xg[128+tid], gg = xg[256+tid], go = xg[384+tid];
      float cn = sigmoid_fast(gf)*c[tid] + sigmoid_fast(gi)*tanh_fast(gg);
      float hn = sigmoid_fast(go)*tanh_fast(cn);
      c[tid]=cn; h[tid]=hn;
    }
    __syncthreads();
    // emit fc input row y = [h | weighted | emb] as f16 hi/lo split (lo x2048), K-padded
    size_t m = (size_t)t*32 + b;
    #pragma unroll
    for(int cb=0; cb<3; ++cb){
      int col = tid + cb*512;
      if(col < KPAD){
        float v;
        if(col<128) v = h[col];
        else if(col<896) v = w_[col-128];
        else if(col<1096) v = emb[col-896];
        else v = 0.f;
        _Float16 hi = (_Float16)v;
        Ahi[m*KPAD + col] = hi;
        Alo[m*KPAD + col] = (_Float16)((v - (float)hi) * 2048.0f);
      }
    }
    __syncthreads();
  }
}

// ============ split-f16 MFMA GEMM: C = (Ahi+Alo/2048) . (Bhi+Blo/2048)^T / 64 ============
// BM=128, BN=128, BK=32, 256 threads (4 waves, 2x2 wave grid of 64x64)
__global__ __launch_bounds__(256) void gemm_fc(
    const _Float16* __restrict__ Ahi, const _Float16* __restrict__ Alo,
    const _Float16* __restrict__ Bhi, const _Float16* __restrict__ Blo,
    const float* __restrict__ fcb,
    float* __restrict__ out, unsigned long long* __restrict__ part){
  int blk = blockIdx.x;
  int mb = blk % NB_M, nb = blk / NB_M;       // mb fast: consecutive blocks share B tile in L2
  int m0 = mb*128, n0 = nb*128;
  int tid = threadIdx.x;
  int lane = tid & 63, wv = tid >> 6;
  int wm = (wv & 1)*64, wn = (wv >> 1)*64;
  int l15 = lane & 15, q = lane >> 4;
  __shared__ _Float16 Ahs[128*40];            // pitch 40 f16 = 80B
  __shared__ _Float16 Als[128*40];
  __shared__ _Float16 Bhs[128*40];
  __shared__ _Float16 Bls[128*40];
  __shared__ unsigned long long pl[128*2];
  floatx4 acc1[4][4] = {};                    // hi*hi
  floatx4 acc2[4][4] = {};                    // hi*lo + lo*hi   (scale 1/2048)
  for(int p=0;p<35;++p){
    __syncthreads();
    #pragma unroll
    for(int i=0;i<2;++i){
      int ch = tid + i*256;
      int row = ch >> 2, kc = ch & 3;
      uint4 va = *((const uint4*)(Ahi + (size_t)(m0+row)*KPAD + p*32) + kc);
      uint4 vb = *((const uint4*)(Alo + (size_t)(m0+row)*KPAD + p*32) + kc);
      uint4 vc = *((const uint4*)(Bhi + (size_t)(n0+row)*KPAD + p*32) + kc);
      uint4 vd = *((const uint4*)(Blo + (size_t)(n0+row)*KPAD + p*32) + kc);
      *(uint4*)&Ahs[row*40 + kc*8] = va;
      *(uint4*)&Als[row*40 + kc*8] = vb;
      *(uint4*)&Bhs[row*40 + kc*8] = vc;
      *(uint4*)&Bls[row*40 + kc*8] = vd;
    }
    __syncthreads();
    half8 bh[4], bl[4];
    #pragma unroll
    for(int ni=0;ni<4;++ni){
      bh[ni] = *(half8*)&Bhs[(wn+ni*16+l15)*40 + q*8];
      bl[ni] = *(half8*)&Bls[(wn+ni*16+l15)*40 + q*8];
    }
    #pragma unroll
    for(int mi=0;mi<4;++mi){
      half8 ah = *(half8*)&Ahs[(wm+mi*16+l15)*40 + q*8];
      half8 al = *(half8*)&Als[(wm+mi*16+l15)*40 + q*8];
      #pragma unroll
      for(int ni=0;ni<4;++ni){
        acc1[mi][ni] = __builtin_amdgcn_mfma_f32_16x16x32_f16(ah, bh[ni], acc1[mi][ni],0,0,0);
        acc2[mi][ni] = __builtin_amdgcn_mfma_f32_16x16x32_f16(ah, bl[ni], acc2[mi][ni],0,0,0);
        acc2[mi][ni] = __builtin_amdgcn_mfma_f32_16x16x32_f16(al, bh[ni], acc2[mi][ni],0,0,0);
      }
    }
  }
  // epilogue: unscale, +bias, fp32 store, per-row argmax from fp32 accs
  const float S1 = 1.0f/64.0f;
  const float S2 = 1.0f/(64.0f*2048.0f);
  float fcbv[4];
  #pragma unroll
  for(int ni=0;ni<4;++ni) fcbv[ni] = fcb[n0+wn+ni*16+l15];
  #pragma unroll
  for(int mi=0;mi<4;++mi){
    #pragma unroll
    for(int r=0;r<4;++r){
      int gm = m0 + wm + mi*16 + q*4 + r;
      bool valid = gm < MROWS;
      int tt = gm >> 5, bb = gm & 31;
      size_t obase = (size_t)bb*T_*VOCAB + (size_t)(tt+1)*VOCAB;
      float bestv = -3.4e38f; int bestc = 0;
      #pragma unroll
      for(int ni=0;ni<4;++ni){
        int gn = n0 + wn + ni*16 + l15;
        float val = acc1[mi][ni][r]*S1 + acc2[mi][ni][r]*S2 + fcbv[ni];
        if(valid) out[obase + gn] = val;
        if(val > bestv){ bestv = val; bestc = gn; }
      }
      unsigned int ku = __float_as_uint(bestv);
      ku = (ku & 0x80000000u) ? ~ku : (ku | 0x80000000u);
      unsigned long long key = ((unsigned long long)ku<<32)
                             | (unsigned long long)(0xFFFFFFFFu - (unsigned int)bestc);
      #pragma unroll
      for(int off=1; off<16; off<<=1){
        unsigned long long o = __shfl_xor(key, off);
        key = (o > key) ? o : key;
      }
      if(l15==0){
        int row_local = wm + mi*16 + q*4 + r;
        pl[row_local*2 + (wv>>1)] = key;
      }
    }
  }
  __syncthreads();
  if(tid < 128){
    unsigned long long k0 = pl[tid*2], k1 = pl[tid*2+1];
    unsigned long long k = k0>k1?k0:k1;
    int gm = m0 + tid;
    if(gm < MROWS) part[(size_t)nb*MPAD + gm] = k;
  }
}

// ============ final argmax over 250 column-block partials ============
__global__ void argmax_final(const unsigned long long* __restrict__ part,
                             float* __restrict__ out){
  int m = blockIdx.x;          // 0..3039
  int lane = threadIdx.x;      // 64
  unsigned long long k = 0;
  for(int nb=lane; nb<NB_N; nb+=64){
    unsigned long long v = part[(size_t)nb*MPAD + m];
    if(v>k) k=v;
  }
  for(int off=32;off;off>>=1){
    unsigned long long o = __shfl_xor(k, off);
    if(o>k) k=o;
  }
  if(lane==0){
    unsigned int col = 0xFFFFFFFFu - (unsigned int)(k & 0xFFFFFFFFull);
    int tt = m >> 5, bb = m & 31;
    out[(size_t)B_*T_*VOCAB + (size_t)bb*T_ + (tt+1)] = (float)col;
  }
}

extern "C" void kernel_launch(void* const* d_in, const int* in_sizes, int n_in,
                              void* d_out, int out_size, void* d_ws, size_t ws_size,
                              hipStream_t stream){
  const float* enc       = (const float*)d_in[0];
  const int*   trg       = (const int*)d_in[1];
  const float* embedding = (const float*)d_in[2];
  const float* attn_W    = (const float*)d_in[3];
  const float* attn_b    = (const float*)d_in[4];
  const float* attn_v    = (const float*)d_in[5];
  const float* W_ih      = (const float*)d_in[6];
  const float* W_hh      = (const float*)d_in[7];
  const float* b_ih      = (const float*)d_in[8];
  const float* b_hh      = (const float*)d_in[9];
  const float* fcW       = (const float*)d_in[10];
  const float* fcb       = (const float*)d_in[11];
  float* out = (float*)d_out;
  char* ws = (char*)d_ws;
  _Float16* Ahi = (_Float16*)(ws + WS_AHI);
  _Float16* Alo = (_Float16*)(ws + WS_ALO);
  _Float16* Bhi = (_Float16*)(ws + WS_BHI);
  _Float16* Blo = (_Float16*)(ws + WS_BLO);
  unsigned long long* part = (unsigned long long*)(ws + WS_PART);
  float2* W1T = (float2*)(ws + WS_W1T);
  float2* W2T = (float2*)(ws + WS_W2T);
  float* encT  = (float*)(ws + WS_ENCT);
  float* gbias = (float*)(ws + WS_GB);

  prep_weights<<<(281088+255)/256, 256, 0, stream>>>(W_ih, W_hh, b_ih, b_hh, W1T, W2T, gbias);
  prep_encpart<<<1024, 128, 0, stream>>>(enc, attn_W, attn_b, encT);
  prep_B<<<140000, 256, 0, stream>>>(fcW, Bhi, Blo);
  zero_t0<<<(B_*VOCAB + B_ + 255)/256, 256, 0, stream>>>(out);
  recurrence<<<32, 512, 0, stream>>>(enc, trg, embedding, attn_W, attn_v,
                                     W1T, W2T, gbias, encT, Ahi, Alo);
  gemm_fc<<<NB_M*NB_N, 256, 0, stream>>>(Ahi, Alo, Bhi, Blo, fcb, out, part);
  argmax_final<<<MROWS, 64, 0, stream>>>(part, out);
}